// Round 1
// baseline (190.083 us; speedup 1.0000x reference)
//
#include <hip/hip_runtime.h>

// GenomeNet: B=4096, N_IN=W=N_OUT=1024, L=8 hidden layers, D=16 fan-in.
// Strategy: batch tile of TB=16 rows per block (1 block/CU), activations live
// in LDS batch-major with padded stride 1025 (bank = (node + b) % 32).
// Thread t evaluates node t: 16 idx/wgt via int4/float4, 16x16 ds_read_b32
// gathers (b-offset folded into the 16-bit DS immediate), f32 accumulate,
// fast tanh (v_exp_f32 + v_rcp_f32). Ping-pong two 64KB LDS buffers.

#define TB       16
#define LSTRIDE  1025      // floats per batch row: +1 pad rotates banks
#define W_NODES  1024
#define LAYERS   8

__device__ __forceinline__ float fast_tanh(float x) {
    // tanh(x) = 1 - 2/(e^{2x}+1); e^{2x} = 2^(x * 2*log2(e)).
    // a -> inf gives +1, a -> 0 gives -1; no NaN for finite x.
    float a = __builtin_amdgcn_exp2f(x * 2.8853900817779268f);
    return 1.0f - 2.0f * __builtin_amdgcn_rcpf(a + 1.0f);
}

__device__ __forceinline__ void gstep(const float* rd, int s, float w, float* acc) {
    const float* c = rd + s;                 // byte offsets b*4100 fit DS imm16
    #pragma unroll
    for (int b = 0; b < TB; ++b)
        acc[b] = fmaf(c[b * LSTRIDE], w, acc[b]);
}

__device__ __forceinline__ void gquad(const float* rd, int4 s, float4 w, float* acc) {
    gstep(rd, s.x, w.x, acc);
    gstep(rd, s.y, w.y, acc);
    gstep(rd, s.z, w.z, acc);
    gstep(rd, s.w, w.w, acc);
}

__global__ __launch_bounds__(1024) void genome_net(
    const float* __restrict__ x,
    const int*   __restrict__ src_hidden,
    const float* __restrict__ w_hidden,
    const int*   __restrict__ src_out,
    const float* __restrict__ w_out,
    float*       __restrict__ out)
{
    extern __shared__ float lds[];
    float* bufA = lds;                       // [TB][LSTRIDE]
    float* bufB = lds + TB * LSTRIDE;

    const int t  = threadIdx.x;              // node / output index, 0..1023
    const int b0 = blockIdx.x * TB;          // batch tile base

    // Stage x tile: lane-consecutive writes -> banks (j + t) % 32, conflict-free.
    #pragma unroll
    for (int j = 0; j < TB; ++j)
        bufA[j * LSTRIDE + t] = x[(size_t)(b0 + j) * W_NODES + t];
    __syncthreads();

    float* rd = bufA;
    float* wr = bufB;

    #pragma unroll 1
    for (int l = 0; l < LAYERS; ++l) {
        const int row = (l << 10) + t;       // [L,W,D] flat row
        const int4*   sp = (const int4*)(src_hidden) + (row << 2);
        const float4* wp = (const float4*)(w_hidden) + (row << 2);
        int4   s0 = sp[0], s1 = sp[1], s2 = sp[2], s3 = sp[3];
        float4 w0 = wp[0], w1 = wp[1], w2 = wp[2], w3 = wp[3];

        float acc[TB];
        #pragma unroll
        for (int b = 0; b < TB; ++b) acc[b] = 0.0f;

        gquad(rd, s0, w0, acc);
        gquad(rd, s1, w1, acc);
        gquad(rd, s2, w2, acc);
        gquad(rd, s3, w3, acc);

        #pragma unroll
        for (int b = 0; b < TB; ++b)
            wr[b * LSTRIDE + t] = fast_tanh(acc[b]);

        __syncthreads();                     // wr complete; rd free to overwrite
        float* tmp = rd; rd = wr; wr = tmp;
    }

    // Output layer: identity activation, gather from rd (== bufA after 8 swaps).
    {
        const int4*   sp = (const int4*)(src_out) + (t << 2);
        const float4* wp = (const float4*)(w_out) + (t << 2);
        int4   s0 = sp[0], s1 = sp[1], s2 = sp[2], s3 = sp[3];
        float4 w0 = wp[0], w1 = wp[1], w2 = wp[2], w3 = wp[3];

        float acc[TB];
        #pragma unroll
        for (int b = 0; b < TB; ++b) acc[b] = 0.0f;

        gquad(rd, s0, w0, acc);
        gquad(rd, s1, w1, acc);
        gquad(rd, s2, w2, acc);
        gquad(rd, s3, w3, acc);

        // Lane-consecutive t -> coalesced 256B stores per b.
        #pragma unroll
        for (int b = 0; b < TB; ++b)
            out[(size_t)(b0 + b) * W_NODES + t] = acc[b];
    }
}

extern "C" void kernel_launch(void* const* d_in, const int* in_sizes, int n_in,
                              void* d_out, int out_size, void* d_ws, size_t ws_size,
                              hipStream_t stream) {
    const float* x  = (const float*)d_in[0];
    const int*   sh = (const int*)  d_in[1];
    const float* wh = (const float*)d_in[2];
    const int*   so = (const int*)  d_in[3];
    const float* wo = (const float*)d_in[4];
    float* out = (float*)d_out;

    const int shmem = 2 * TB * LSTRIDE * (int)sizeof(float);   // 131200 B
    hipFuncSetAttribute(reinterpret_cast<const void*>(genome_net),
                        hipFuncAttributeMaxDynamicSharedMemorySize, shmem);

    genome_net<<<dim3(4096 / TB), dim3(1024), shmem, stream>>>(x, sh, wh, so, wo, out);
}

// Round 2
// 149.253 us; speedup vs baseline: 1.2736x; 1.2736x over previous
//
#include <hip/hip_runtime.h>

// GenomeNet: B=4096, N_IN=W=N_OUT=1024, L=8 hidden, D=16 fan-in.
// R2: node-major LDS activations — node s's TB=16 batch values contiguous
// (64 B) so one edge-gather = 4 x ds_read_b128 (was 16 x ds_read_b32).
// Bank decorrelation via XOR swizzle of 16B quads: quad q of node s lives at
// slot q ^ ((s>>1)&3); combined with 16*(s&1) this spreads lanes uniformly
// over all 8 four-bank groups. Buffers: 2 x 64 KB ping-pong (128 KB LDS).

#define TB        16
#define W_NODES   1024
#define LAYERS    8
#define BUF_FL    (W_NODES * TB)   // 16384 floats = 64 KB

__device__ __forceinline__ float fast_tanh(float x) {
    float a = __builtin_amdgcn_exp2f(x * 2.8853900817779268f);
    return 1.0f - 2.0f * __builtin_amdgcn_rcpf(a + 1.0f);
}

// float-index of quad slot 0 for node s, with swizzle bits ((s>>1)&3)<<2
// folded into bits [3:2]; quad q is at base ^ (q<<2).
__device__ __forceinline__ int swz_base(int s) {
    return (s << 4) | ((s << 1) & 0xC);
}

__device__ __forceinline__ void gather_node(const float* rd, int s, float w, float* acc) {
    const int base = swz_base(s);
    #pragma unroll
    for (int q = 0; q < 4; ++q) {
        const float4 v = *(const float4*)(rd + (base ^ (q << 2)));
        acc[4 * q + 0] = fmaf(v.x, w, acc[4 * q + 0]);
        acc[4 * q + 1] = fmaf(v.y, w, acc[4 * q + 1]);
        acc[4 * q + 2] = fmaf(v.z, w, acc[4 * q + 2]);
        acc[4 * q + 3] = fmaf(v.w, w, acc[4 * q + 3]);
    }
}

__device__ __forceinline__ void gquad(const float* rd, int4 s, float4 w, float* acc) {
    gather_node(rd, s.x, w.x, acc);
    gather_node(rd, s.y, w.y, acc);
    gather_node(rd, s.z, w.z, acc);
    gather_node(rd, s.w, w.w, acc);
}

// Write thread t's 16 values (already in vals[0..15]) to its node row, swizzled.
__device__ __forceinline__ void write_node(float* wr, int t, const float* vals) {
    const int base = swz_base(t);
    #pragma unroll
    for (int q = 0; q < 4; ++q) {
        float4 v;
        v.x = vals[4 * q + 0];
        v.y = vals[4 * q + 1];
        v.z = vals[4 * q + 2];
        v.w = vals[4 * q + 3];
        *(float4*)(wr + (base ^ (q << 2))) = v;
    }
}

__global__ __launch_bounds__(1024) void genome_net(
    const float* __restrict__ x,
    const int*   __restrict__ src_hidden,
    const float* __restrict__ w_hidden,
    const int*   __restrict__ src_out,
    const float* __restrict__ w_out,
    float*       __restrict__ out)
{
    extern __shared__ float lds[];
    float* bufA = lds;                 // [1024 nodes][16 batch] swizzled
    float* bufB = lds + BUF_FL;

    const int t  = threadIdx.x;        // node / output index
    const int b0 = blockIdx.x * TB;    // batch tile base

    // Stage x: thread t gathers input node t's 16 batch values (coalesced
    // across lanes per j), then writes its own row — conflict-free b128s.
    {
        float xv[TB];
        #pragma unroll
        for (int j = 0; j < TB; ++j)
            xv[j] = x[(size_t)(b0 + j) * W_NODES + t];
        write_node(bufA, t, xv);
    }
    __syncthreads();

    float* rd = bufA;
    float* wr = bufB;

    #pragma unroll 1
    for (int l = 0; l < LAYERS; ++l) {
        const int row = (l << 10) + t;
        const int4*   sp = (const int4*)(src_hidden) + (row << 2);
        const float4* wp = (const float4*)(w_hidden) + (row << 2);
        int4   s0 = sp[0], s1 = sp[1], s2 = sp[2], s3 = sp[3];
        float4 w0 = wp[0], w1 = wp[1], w2 = wp[2], w3 = wp[3];

        float acc[TB];
        #pragma unroll
        for (int b = 0; b < TB; ++b) acc[b] = 0.0f;

        gquad(rd, s0, w0, acc);
        gquad(rd, s1, w1, acc);
        gquad(rd, s2, w2, acc);
        gquad(rd, s3, w3, acc);

        float act[TB];
        #pragma unroll
        for (int b = 0; b < TB; ++b) act[b] = fast_tanh(acc[b]);
        write_node(wr, t, act);

        __syncthreads();
        float* tmp = rd; rd = wr; wr = tmp;
    }

    // Output layer: identity activation; coalesced global stores.
    {
        const int4*   sp = (const int4*)(src_out) + (t << 2);
        const float4* wp = (const float4*)(w_out) + (t << 2);
        int4   s0 = sp[0], s1 = sp[1], s2 = sp[2], s3 = sp[3];
        float4 w0 = wp[0], w1 = wp[1], w2 = wp[2], w3 = wp[3];

        float acc[TB];
        #pragma unroll
        for (int b = 0; b < TB; ++b) acc[b] = 0.0f;

        gquad(rd, s0, w0, acc);
        gquad(rd, s1, w1, acc);
        gquad(rd, s2, w2, acc);
        gquad(rd, s3, w3, acc);

        #pragma unroll
        for (int b = 0; b < TB; ++b)
            out[(size_t)(b0 + b) * W_NODES + t] = acc[b];
    }
}

extern "C" void kernel_launch(void* const* d_in, const int* in_sizes, int n_in,
                              void* d_out, int out_size, void* d_ws, size_t ws_size,
                              hipStream_t stream) {
    const float* x  = (const float*)d_in[0];
    const int*   sh = (const int*)  d_in[1];
    const float* wh = (const float*)d_in[2];
    const int*   so = (const int*)  d_in[3];
    const float* wo = (const float*)d_in[4];
    float* out = (float*)d_out;

    const int shmem = 2 * BUF_FL * (int)sizeof(float);   // 131072 B
    hipFuncSetAttribute(reinterpret_cast<const void*>(genome_net),
                        hipFuncAttributeMaxDynamicSharedMemorySize, shmem);

    genome_net<<<dim3(4096 / TB), dim3(1024), shmem, stream>>>(x, sh, wh, so, wo, out);
}

// Round 3
// 116.695 us; speedup vs baseline: 1.6289x; 1.2790x over previous
//
#include <hip/hip_runtime.h>

// GenomeNet: B=4096, N_IN=W=N_OUT=1024, L=8 hidden, D=16 fan-in.
// R3: fp16 activation storage (fp32 accumulate) — node row = 16 batch x 2B
// = 32 B, so an edge-gather is 2 x ds_read_b128 serviced by 2 lanes sharing
// the node (lane = (n_sub 0..31, ch 0..1)). Gather instr count per CU halves
// vs R2 (4608 vs 9216) and each instruction reads 32 whole rows (less bank
// imbalance than 64 independent chunks). Ping-pong 2 x 32 KB LDS buffers.

#define TB       16
#define W_NODES  1024
#define LAYERS   8
#define ROW_H    16                    // halfs per node row
#define BUF_H    (W_NODES * ROW_H)     // 16384 halfs = 32 KB

typedef _Float16 h8 __attribute__((ext_vector_type(8)));

__device__ __forceinline__ float fast_tanh(float x) {
    // tanh(x) = 1 - 2/(e^{2x}+1); monotone, max err ~ulp-level vs libm tanh.
    float a = __builtin_amdgcn_exp2f(x * 2.8853900817779268f);
    return 1.0f - 2.0f * __builtin_amdgcn_rcpf(a + 1.0f);
}

__global__ __launch_bounds__(1024) void genome_net(
    const float* __restrict__ x,
    const int*   __restrict__ src_hidden,
    const float* __restrict__ w_hidden,
    const int*   __restrict__ src_out,
    const float* __restrict__ w_out,
    float*       __restrict__ out)
{
    extern __shared__ _Float16 lds[];
    _Float16* bufA = lds;              // [1024 nodes][16 batch] fp16
    _Float16* bufB = lds + BUF_H;

    const int tid  = threadIdx.x;
    const int wave = tid >> 6;         // 0..15
    const int lane = tid & 63;
    const int nsub = lane & 31;        // node within wave-group
    const int ch   = lane >> 5;        // batch half: 0 -> b0..7, 1 -> b8..15
    const int b0   = blockIdx.x * TB;

    // ---- Stage x: fp32 -> fp16 rows. Lane (nsub,ch) owns chunk ch of node n.
    #pragma unroll
    for (int r = 0; r < 2; ++r) {
        const int n = (r << 9) + (wave << 5) + nsub;
        h8 hv;
        #pragma unroll
        for (int j = 0; j < 8; ++j)
            hv[j] = (_Float16)x[(size_t)(b0 + (ch << 3) + j) * W_NODES + n];
        *(h8*)(bufA + n * ROW_H + (ch << 3)) = hv;
    }
    __syncthreads();

    _Float16* rd = bufA;
    _Float16* wr = bufB;

    #pragma unroll 1
    for (int l = 0; l < LAYERS; ++l) {
        #pragma unroll 1
        for (int r = 0; r < 2; ++r) {
            const int n   = (r << 9) + (wave << 5) + nsub;
            const int row = (l << 10) + n;
            const int4*   sp = (const int4*)(src_hidden) + (row << 2);
            const float4* wp = (const float4*)(w_hidden) + (row << 2);
            int4   s4[4]; float4 w4[4];
            #pragma unroll
            for (int q = 0; q < 4; ++q) { s4[q] = sp[q]; w4[q] = wp[q]; }
            int   s_arr[16]; float w_arr[16];
            #pragma unroll
            for (int q = 0; q < 4; ++q) {
                s_arr[4*q+0] = s4[q].x; s_arr[4*q+1] = s4[q].y;
                s_arr[4*q+2] = s4[q].z; s_arr[4*q+3] = s4[q].w;
                w_arr[4*q+0] = w4[q].x; w_arr[4*q+1] = w4[q].y;
                w_arr[4*q+2] = w4[q].z; w_arr[4*q+3] = w4[q].w;
            }

            float acc[8];
            #pragma unroll
            for (int j = 0; j < 8; ++j) acc[j] = 0.0f;

            #pragma unroll
            for (int d = 0; d < 16; ++d) {
                const h8 v = *(const h8*)(rd + (s_arr[d] << 4) + (ch << 3));
                const float w = w_arr[d];
                #pragma unroll
                for (int j = 0; j < 8; ++j)
                    acc[j] = fmaf((float)v[j], w, acc[j]);
            }

            h8 hv;
            #pragma unroll
            for (int j = 0; j < 8; ++j) hv[j] = (_Float16)fast_tanh(acc[j]);
            *(h8*)(wr + n * ROW_H + (ch << 3)) = hv;
        }
        __syncthreads();               // both rounds written; rd reusable
        _Float16* tmp = rd; rd = wr; wr = tmp;
    }

    // ---- Output layer: identity activation, fp32 global stores.
    #pragma unroll 1
    for (int r = 0; r < 2; ++r) {
        const int n = (r << 9) + (wave << 5) + nsub;
        const int4*   sp = (const int4*)(src_out) + (n << 2);
        const float4* wp = (const float4*)(w_out) + (n << 2);
        int4   s4[4]; float4 w4[4];
        #pragma unroll
        for (int q = 0; q < 4; ++q) { s4[q] = sp[q]; w4[q] = wp[q]; }
        int   s_arr[16]; float w_arr[16];
        #pragma unroll
        for (int q = 0; q < 4; ++q) {
            s_arr[4*q+0] = s4[q].x; s_arr[4*q+1] = s4[q].y;
            s_arr[4*q+2] = s4[q].z; s_arr[4*q+3] = s4[q].w;
            w_arr[4*q+0] = w4[q].x; w_arr[4*q+1] = w4[q].y;
            w_arr[4*q+2] = w4[q].z; w_arr[4*q+3] = w4[q].w;
        }

        float acc[8];
        #pragma unroll
        for (int j = 0; j < 8; ++j) acc[j] = 0.0f;

        #pragma unroll
        for (int d = 0; d < 16; ++d) {
            const h8 v = *(const h8*)(rd + (s_arr[d] << 4) + (ch << 3));
            const float w = w_arr[d];
            #pragma unroll
            for (int j = 0; j < 8; ++j)
                acc[j] = fmaf((float)v[j], w, acc[j]);
        }

        // For fixed j, the 32 lanes of a ch-half store 128 consecutive bytes.
        #pragma unroll
        for (int j = 0; j < 8; ++j)
            out[(size_t)(b0 + (ch << 3) + j) * W_NODES + n] = acc[j];
    }
}

extern "C" void kernel_launch(void* const* d_in, const int* in_sizes, int n_in,
                              void* d_out, int out_size, void* d_ws, size_t ws_size,
                              hipStream_t stream) {
    const float* x  = (const float*)d_in[0];
    const int*   sh = (const int*)  d_in[1];
    const float* wh = (const float*)d_in[2];
    const int*   so = (const int*)  d_in[3];
    const float* wo = (const float*)d_in[4];
    float* out = (float*)d_out;

    const int shmem = 2 * BUF_H * (int)sizeof(_Float16);   // 65536 B
    hipFuncSetAttribute(reinterpret_cast<const void*>(genome_net),
                        hipFuncAttributeMaxDynamicSharedMemorySize, shmem);

    genome_net<<<dim3(4096 / TB), dim3(1024), shmem, stream>>>(x, sh, wh, so, wo, out);
}